// Round 3
// baseline (380.542 us; speedup 1.0000x reference)
//
#include <hip/hip_runtime.h>
#include <hip/hip_bf16.h>

typedef __attribute__((ext_vector_type(8))) short bf16x8;
typedef __attribute__((ext_vector_type(4))) float f32x4;
typedef __attribute__((ext_vector_type(2))) float f32x2;

static __device__ __forceinline__ float bf2f(unsigned short u){
  return __uint_as_float(((unsigned)u) << 16);
}
static __device__ __forceinline__ unsigned short f2bf(float f){
  unsigned u = __float_as_uint(f);
  u += 0x7FFFu + ((u >> 16) & 1u);
  return (unsigned short)(u >> 16);
}
static __device__ __forceinline__ void gload_lds16(const void* g, void* l){
  __builtin_amdgcn_global_load_lds((const __attribute__((address_space(1))) unsigned int*)g,
                                   (__attribute__((address_space(3))) unsigned int*)l, 16, 0, 0);
}

#define MFMA16(acc, a, b) (acc) = __builtin_amdgcn_mfma_f32_16x16x32_bf16((a),(b),(acc),0,0,0)

#define NB   8
#define NVRT 2562
#define MP   2624      /* rows padded to 82*32 */
#define NRB2 82        /* 32-row blocks */
#define NKT  41        /* K tiles of 64 over MP */

// channel-last bf16 feature-map buffer bases (elements)
#define FT_B0 0ul
#define FT_B1 6422528ul
#define FT_B2 9633792ul
#define FT_B3 11239424ul
#define FT_TOT 12042240ul

// ---------------------------------------------------------------- unified transpose: 4 maps, [B,C,H,W]f32 -> [B,HW,C]bf16
__global__ void k_transpose_all(const float* __restrict__ c0, const float* __restrict__ c1,
                                const float* __restrict__ c2, const float* __restrict__ c3,
                                unsigned short* __restrict__ ftT)
{
  __shared__ float tile[32][33];
  int bx = blockIdx.x, b = blockIdx.y;
  int m, local;
  if (bx < 784)      { m = 0; local = bx; }
  else if (bx < 1184){ m = 1; local = bx - 784; }
  else if (bx < 1408){ m = 2; local = bx - 1184; }
  else               { m = 3; local = bx - 1408; }
  int HW  = (m==0)?3136:(m==1)?784:(m==2)?196:49;
  int C   = 256 << m;
  int nbx = (m==0)?98:(m==1)?25:(m==2)?7:2;
  size_t fb = (m==0)?FT_B0:(m==1)?FT_B1:(m==2)?FT_B2:FT_B3;
  const float* src = (m==0)?c0:(m==1)?c1:(m==2)?c2:c3;

  int hw0 = (local % nbx) * 32, c0i = (local / nbx) * 32;
  int tx = threadIdx.x, ty = threadIdx.y;
  const float* s = src + (size_t)b * C * HW;
#pragma unroll
  for (int i = 0; i < 4; i++){
    int c = c0i + ty + i*8, hw = hw0 + tx;
    tile[ty + i*8][tx] = (c < C && hw < HW) ? s[(size_t)c * HW + hw] : 0.f;
  }
  __syncthreads();
  unsigned short* d = ftT + fb + (size_t)b * HW * C;
#pragma unroll
  for (int i = 0; i < 4; i++){
    int hw = hw0 + ty + i*8, c = c0i + tx;
    if (hw < HW && c < C) d[(size_t)hw * C + c] = f2bf(tile[tx][ty + i*8]);
  }
}

// ---------------------------------------------------------------- unified weight pack: 7 weights -> [Kp/8][128][8] bf16
struct PWArgs {
  const float* src[7];
  unsigned short* dst[7];
  int ksrc[7], nsrc[7];
};
__global__ void k_packw_all(PWArgs a)
{
  const int cb[8] = {0,491520,528384,565248,585728,606208,626688,647168};
  int g = blockIdx.x * 256 + threadIdx.x;
#pragma unroll
  for (int s = 0; s < 7; s++){
    if (g >= cb[s] && g < cb[s+1]){
      int li = g - cb[s];
      int k = li >> 7, c = li & 127;
      int ks = a.ksrc[s], ns = a.nsrc[s];
      float v = (k < ks) ? a.src[s][(size_t)k * ns + c] : 0.f;
      a.dst[s][((size_t)(k >> 3) * 128 + c) * 8 + (k & 7)] = f2bf(v);
    }
  }
}

// ---------------------------------------------------------------- pack adjacency f32 -> bf16 MFMA tiles with baked XOR swizzle
__global__ void k_adjpack(const float* __restrict__ adj, unsigned short* __restrict__ adjP)
{
  int kt = blockIdx.x, rb = blockIdx.y, b = blockIdx.z;
  int t = threadIdx.x, row = t >> 3, k8 = t & 7;
  int grow = rb*32 + row, gk = kt*64 + k8*8;
  unsigned short o[8];
  if (grow < NVRT && gk + 8 <= NVRT){
    const float2* p = (const float2*)(adj + ((size_t)b*NVRT + grow)*NVRT + gk);
    float2 f0 = p[0], f1 = p[1], f2 = p[2], f3 = p[3];
    o[0]=f2bf(f0.x); o[1]=f2bf(f0.y); o[2]=f2bf(f1.x); o[3]=f2bf(f1.y);
    o[4]=f2bf(f2.x); o[5]=f2bf(f2.y); o[6]=f2bf(f3.x); o[7]=f2bf(f3.y);
  } else if (grow < NVRT){
    const float* ap = adj + ((size_t)b*NVRT + grow)*NVRT;
#pragma unroll
    for (int e = 0; e < 8; e++){ int k = gk + e; o[e] = (k < NVRT) ? f2bf(ap[k]) : 0; }
  } else {
#pragma unroll
    for (int e = 0; e < 8; e++) o[e] = 0;
  }
  bf16x8 h;
#pragma unroll
  for (int e = 0; e < 8; e++) h[e] = (short)o[e];
  char* tb = (char*)(adjP + (((size_t)b*NRB2 + rb)*NKT + kt) * 2048);
  *(bf16x8*)(tb + row*128 + ((k8*16) ^ ((row&7)<<4))) = h;
}

// ---------------------------------------------------------------- meta + vf base cols + zero pads of vf/x1/x2 (fused)
__global__ void k_prep(const float* __restrict__ vfeat, const float* __restrict__ pos,
                       float* __restrict__ meta,
                       unsigned short* __restrict__ vf,
                       unsigned short* __restrict__ x1,
                       unsigned short* __restrict__ x2)
{
  int row = blockIdx.x, b = blockIdx.y;
  size_t vfo = ((size_t)b * MP + row) * 288;
  size_t xo  = ((size_t)b * MP + row) * 160;
  if (row < NVRT){
    size_t src = (size_t)b * NVRT + row;
    if (threadIdx.x < 4){
      int m = threadIdx.x;
      float px = pos[src*3 + 0], py = pos[src*3 + 1];
      px = fminf(fmaxf(px, -1.f), 1.f);
      py = fminf(fmaxf(py, -1.f), 1.f);
      int W  = (m==0)?56:(m==1)?28:(m==2)?14:7;
      int C  = 256 << m;
      int HW = W * W;
      size_t Bm = (m==0)?FT_B0:(m==1)?FT_B1:(m==2)?FT_B2:FT_B3;
      float gx = (px + 1.f) * 0.5f * (float)(W - 1);
      float gy = (py + 1.f) * 0.5f * (float)(W - 1);
      int x0 = (int)floorf(gx), y0 = (int)floorf(gy);
      float wx = gx - (float)x0, wy = gy - (float)y0;
      int x1i = min(x0 + 1, W - 1), y1i = min(y0 + 1, W - 1);
      size_t base = Bm + (size_t)b * HW * C;
      float* mo = meta + src * 32 + m * 8;
      mo[0] = __int_as_float((int)(base + ((size_t)y0  * W + x0 ) * C));
      mo[1] = __int_as_float((int)(base + ((size_t)y0  * W + x1i) * C));
      mo[2] = __int_as_float((int)(base + ((size_t)y1i * W + x0 ) * C));
      mo[3] = __int_as_float((int)(base + ((size_t)y1i * W + x1i) * C));
      mo[4] = (1.f-wx)*(1.f-wy);
      mo[5] = wx*(1.f-wy);
      mo[6] = (1.f-wx)*wy;
      mo[7] = wx*wy;
    }
    for (int c = threadIdx.x; c < 288; c += blockDim.x){
      if (c < 128)       vf[vfo + c] = f2bf(vfeat[src*128 + c]);
      else if (c < 131)  vf[vfo + c] = f2bf(pos[src*3 + (c - 128)]);
      else if (c >= 259) vf[vfo + c] = 0;
    }
    for (int c = threadIdx.x; c < 160; c += blockDim.x){
      if (c < 3){
        unsigned short v = f2bf(pos[src*3 + c]);
        x1[xo + c] = v; x2[xo + c] = v;
      } else if (c >= 131){
        x1[xo + c] = 0; x2[xo + c] = 0;
      }
    }
  } else {
    for (int c = threadIdx.x; c < 288; c += blockDim.x) vf[vfo + c] = 0;
    for (int c = threadIdx.x; c < 160; c += blockDim.x){ x1[xo + c] = 0; x2[xo + c] = 0; }
  }
}

// ---------------------------------------------------------------- split-K fused vert_align + lin0 GEMM -> f32 partials
// grid (82, 4 splits, 8); split kt ranges {0,16,32,48,60} (even sizes)
__global__ __launch_bounds__(256) void k_lin0s(
    const unsigned short* __restrict__ ftT,
    const float* __restrict__ meta,
    const unsigned short* __restrict__ wp,
    float* __restrict__ pl0)
{
  __shared__ __align__(16) unsigned short abuf[2][2048];
  __shared__ float smeta[32][33];
  int rb = blockIdx.x * 32, split = blockIdx.y, b = blockIdx.z;
  int t = threadIdx.x, wave = t >> 6, lane = t & 63;
  for (int i = t; i < 1024; i += 256){
    int v = i >> 5, q = i & 31;
    int row = rb + v;
    smeta[v][q] = (row < NVRT) ? meta[((size_t)b * NVRT + row) * 32 + q] : 0.f;
  }
  __syncthreads();

  int srow = t >> 3, k8 = t & 7;
  bool valid = (rb + srow) < NVRT;
  int swst = (srow & 7) << 4;
  int l15 = lane & 15, l4 = lane >> 4;
  int s = split * 16, e = min(s + 16, 60);

  f32x4 acc[2][2];
#pragma unroll
  for (int i = 0; i < 2; i++)
#pragma unroll
    for (int j = 0; j < 2; j++) acc[i][j] = (f32x4){0,0,0,0};

  auto mapof = [](int kt){ return (kt < 4) ? 0 : (kt < 12) ? 1 : (kt < 28) ? 2 : 3; };

  auto issue = [&](int kt, bf16x8& A, bf16x8& Bv, bf16x8& C, bf16x8& D){
    int m = mapof(kt);
    int koff = (m==0) ? 0 : (m==1) ? 256 : (m==2) ? 768 : 1792;
    int kk = kt*64 - koff + k8*8;
    if (valid){
      A  = *(const bf16x8*)(ftT + __float_as_int(smeta[srow][m*8+0]) + kk);
      Bv = *(const bf16x8*)(ftT + __float_as_int(smeta[srow][m*8+1]) + kk);
      C  = *(const bf16x8*)(ftT + __float_as_int(smeta[srow][m*8+2]) + kk);
      D  = *(const bf16x8*)(ftT + __float_as_int(smeta[srow][m*8+3]) + kk);
    } else {
#pragma unroll
      for (int ee = 0; ee < 8; ee++){ A[ee]=0; Bv[ee]=0; C[ee]=0; D[ee]=0; }
    }
  };

  auto blendwrite = [&](int kt, int bufi, bf16x8 A, bf16x8 Bv, bf16x8 C, bf16x8 D){
    int m = mapof(kt);
    float w00 = smeta[srow][m*8+4], w01 = smeta[srow][m*8+5];
    float w10 = smeta[srow][m*8+6], w11 = smeta[srow][m*8+7];
    bf16x8 h;
#pragma unroll
    for (int ee = 0; ee < 8; ee++){
      float f = w00*bf2f((unsigned short)A[ee]) + w01*bf2f((unsigned short)Bv[ee])
              + w10*bf2f((unsigned short)C[ee]) + w11*bf2f((unsigned short)D[ee]);
      h[ee] = (short)f2bf(f);
    }
    *(bf16x8*)((char*)&abuf[bufi][0] + srow*128 + ((k8*16) ^ swst)) = h;
  };

  auto compute = [&](int kt, int bufi){
    const char* ab = (const char*)&abuf[bufi][0];
    bf16x8 afr[2][2], bfr[2][2];
#pragma unroll
    for (int rf = 0; rf < 2; rf++){
      int row = rf*16 + l15;
      int sw = (row & 7) << 4;
#pragma unroll
      for (int ks = 0; ks < 2; ks++)
        afr[rf][ks] = *(const bf16x8*)(ab + row*128 + ((ks*64 + l4*16) ^ sw));
    }
#pragma unroll
    for (int cf = 0; cf < 2; cf++)
#pragma unroll
      for (int ks = 0; ks < 2; ks++)
        bfr[cf][ks] = *(const bf16x8*)(wp + ((size_t)(kt*8 + ks*4 + l4)*128 + wave*32 + cf*16 + l15)*8);
#pragma unroll
    for (int ks = 0; ks < 2; ks++)
#pragma unroll
      for (int rf = 0; rf < 2; rf++)
#pragma unroll
        for (int cf = 0; cf < 2; cf++)
          MFMA16(acc[rf][cf], afr[rf][ks], bfr[cf][ks]);
  };

  bf16x8 A0,B0,C0,D0, A1,B1,C1,D1;
  issue(s, A0,B0,C0,D0);
  blendwrite(s, 0, A0,B0,C0,D0);
  issue(s+1, A1,B1,C1,D1);
  __syncthreads();
  for (int kt = s; kt < e; kt += 2){
    compute(kt, 0);
    blendwrite(kt+1, 1, A1,B1,C1,D1);
    bool more = (kt + 2 < e);
    if (more) issue(kt+2, A0,B0,C0,D0);
    __syncthreads();
    compute(kt+1, 1);
    if (more){
      blendwrite(kt+2, 0, A0,B0,C0,D0);
      issue(kt+3, A1,B1,C1,D1);
    }
    __syncthreads();
  }

  float* po = pl0 + (((size_t)split*NB + b)*MP)*128;
#pragma unroll
  for (int rf = 0; rf < 2; rf++)
#pragma unroll
    for (int cf = 0; cf < 2; cf++){
      int col = wave*32 + cf*16 + l15;
#pragma unroll
      for (int r = 0; r < 4; r++){
        int row = rb + rf*16 + l4*4 + r;
        po[(size_t)row*128 + col] = acc[rf][cf][r];
      }
    }
}

// ---------------------------------------------------------------- lin0 epilogue: vf[:,131:259] = bf16(sum partials + bias)
__global__ void k_lin0e(const float* __restrict__ pl0, const float* __restrict__ bias,
                        unsigned short* __restrict__ vf)
{
  int idx = blockIdx.x * 256 + threadIdx.x;
  if (idx >= NB * NVRT * 32) return;
  int b = idx / (NVRT * 32);
  int rem = idx - b * (NVRT * 32);
  int row = rem >> 5, c4 = rem & 31, col = c4 * 4;
  size_t o = ((size_t)b * MP + row) * 128 + col;
  const size_t ss = (size_t)NB * MP * 128;
  f32x4 v = *(const f32x4*)(pl0 + o);
  f32x4 v1 = *(const f32x4*)(pl0 + ss + o);
  f32x4 v2 = *(const f32x4*)(pl0 + 2*ss + o);
  f32x4 v3 = *(const f32x4*)(pl0 + 3*ss + o);
  f32x4 bv = *(const f32x4*)(bias + col);
  unsigned short* d = vf + ((size_t)b * MP + row) * 288 + 131 + col;
#pragma unroll
  for (int j = 0; j < 4; j++)
    d[j] = f2bf(v[j] + v1[j] + v2[j] + v3[j] + bv[j]);
}

// ---------------------------------------------------------------- y0 = x@w0 (f32), y1p = pack(x@w1) (bf16)
template<int KX>
__global__ __launch_bounds__(256) void k_xw2(
    const unsigned short* __restrict__ x,
    const unsigned short* __restrict__ wp0,
    const unsigned short* __restrict__ wp1,
    float* __restrict__ y0,
    unsigned short* __restrict__ y1p)
{
  int b = blockIdx.y, rb = blockIdx.x * 32;
  int t = threadIdx.x, wave = t >> 6, lane = t & 63;
  int rf = wave & 1, ch = wave >> 1;
  int l15 = lane & 15, l4 = lane >> 4;
  f32x4 a0[4], a1[4];
#pragma unroll
  for (int c = 0; c < 4; c++){ a0[c] = (f32x4){0,0,0,0}; a1[c] = (f32x4){0,0,0,0}; }
  int row = rb + rf*16 + l15;
  const unsigned short* xp = x + ((size_t)b * MP + row) * KX + l4 * 8;
#pragma unroll
  for (int kb = 0; kb < KX; kb += 32){
    bf16x8 a = *(const bf16x8*)(xp + kb);
    size_t bo = ((size_t)((kb>>3) + l4) * 128 + ch*64 + l15) * 8;
#pragma unroll
    for (int c = 0; c < 4; c++){
      bf16x8 b0 = *(const bf16x8*)(wp0 + bo + c*128);
      MFMA16(a0[c], a, b0);
      bf16x8 b1 = *(const bf16x8*)(wp1 + bo + c*128);
      MFMA16(a1[c], a, b1);
    }
  }
#pragma unroll
  for (int c = 0; c < 4; c++){
    int col = ch*64 + c*16 + l15;
#pragma unroll
    for (int r = 0; r < 4; r++){
      int orow = rb + rf*16 + l4*4 + r;
      y0[((size_t)b * MP + orow) * 128 + col] = a0[c][r];
      y1p[(((size_t)b * (MP/8) + (orow>>3)) * 128 + col) * 8 + (orow & 7)] = f2bf(a1[c][r]);
    }
  }
}

// ---------------------------------------------------------------- split-K adj GEMM from packed bf16 adjacency -> f32 partials
// grid (82, 2 splits, 8); split kt ranges {0,21,41}
__global__ __launch_bounds__(256) void k_adjs(
    const unsigned short* __restrict__ adjP,
    const unsigned short* __restrict__ y1p,
    float* __restrict__ pa)
{
  __shared__ __align__(16) unsigned short abuf[2][2048];
  int rb = blockIdx.x, split = blockIdx.y, b = blockIdx.z;
  int t = threadIdx.x, wave = t >> 6, lane = t & 63;
  int l15 = lane & 15, l4 = lane >> 4;
  int s = split ? 21 : 0, e = split ? NKT : 21;
  const unsigned short* tbase = adjP + (((size_t)b*NRB2 + rb)*NKT) * 2048;
  const unsigned short* y1b = y1p + (size_t)b * (MP/8) * 128 * 8;

  f32x4 acc[2][2];
#pragma unroll
  for (int i = 0; i < 2; i++)
#pragma unroll
    for (int j = 0; j < 2; j++) acc[i][j] = (f32x4){0,0,0,0};

  auto stage = [&](int kt, int bufi){
    gload_lds16(tbase + (size_t)kt*2048 + t*8, &abuf[bufi][wave*512]);
  };

  stage(s, 0);
  __syncthreads();

  for (int kt = s; kt < e; ++kt){
    int cur = (kt - s) & 1;
    if (kt + 1 < e) stage(kt+1, cur ^ 1);
    bf16x8 bfr[2][2];
#pragma unroll
    for (int cf = 0; cf < 2; cf++)
#pragma unroll
      for (int ks = 0; ks < 2; ks++)
        bfr[cf][ks] = *(const bf16x8*)(y1b + ((size_t)(kt*8 + ks*4 + l4)*128 + wave*32 + cf*16 + l15)*8);
    const char* ab = (const char*)&abuf[cur][0];
    bf16x8 afr[2][2];
#pragma unroll
    for (int rf = 0; rf < 2; rf++){
      int row = rf*16 + l15;
      int sw = (row & 7) << 4;
#pragma unroll
      for (int ks = 0; ks < 2; ks++)
        afr[rf][ks] = *(const bf16x8*)(ab + row*128 + ((ks*64 + l4*16) ^ sw));
    }
#pragma unroll
    for (int ks = 0; ks < 2; ks++)
#pragma unroll
      for (int rf = 0; rf < 2; rf++)
#pragma unroll
        for (int cf = 0; cf < 2; cf++)
          MFMA16(acc[rf][cf], afr[rf][ks], bfr[cf][ks]);
    __syncthreads();
  }

  float* po = pa + (((size_t)split*NB + b)*MP)*128;
#pragma unroll
  for (int rf = 0; rf < 2; rf++)
#pragma unroll
    for (int cf = 0; cf < 2; cf++){
      int col = wave*32 + cf*16 + l15;
#pragma unroll
      for (int r = 0; r < 4; r++){
        int row = rb*32 + rf*16 + l4*4 + r;
        po[(size_t)row*128 + col] = acc[rf][cf][r];
      }
    }
}

// ---------------------------------------------------------------- adj epilogue: h = relu(y0+pa0+pa1)
// EPI=0 -> xnext bf16 cols 3..130; EPI=1 -> out_feat f32 + fused lin1 position head
template<int EPI>
__global__ void k_adje(const float* __restrict__ y0, const float* __restrict__ pa,
                       unsigned short* __restrict__ xnext,
                       float* __restrict__ outf,
                       const float* __restrict__ pos,
                       const float* __restrict__ wl1, const float* __restrict__ bl1,
                       float* __restrict__ opos)
{
  const size_t ss = (size_t)NB * MP * 128;
  if (EPI == 0){
    int idx = blockIdx.x * 256 + threadIdx.x;
    if (idx >= NB * NVRT * 32) return;
    int b = idx / (NVRT * 32);
    int rem = idx - b * (NVRT * 32);
    int row = rem >> 5, c4 = rem & 31, col = c4 * 4;
    size_t o = ((size_t)b * MP + row) * 128 + col;
    f32x4 v  = *(const f32x4*)(y0 + o);
    f32x4 p0 = *(const f32x4*)(pa + o);
    f32x4 p1 = *(const f32x4*)(pa + ss + o);
    unsigned short* d = xnext + ((size_t)b * MP + row) * 160 + 3 + col;
#pragma unroll
    for (int j = 0; j < 4; j++)
      d[j] = f2bf(fmaxf(v[j] + p0[j] + p1[j], 0.f));
  } else {
    int grow = blockIdx.x * 4 + (threadIdx.x >> 6);
    int lane = threadIdx.x & 63;
    int b = grow / NVRT, row = grow - b * NVRT;
    int c0 = lane * 2;
    size_t o = ((size_t)b * MP + row) * 128 + c0;
    f32x2 v  = *(const f32x2*)(y0 + o);
    f32x2 p0 = *(const f32x2*)(pa + o);
    f32x2 p1 = *(const f32x2*)(pa + ss + o);
    float v0 = fmaxf(v[0] + p0[0] + p1[0], 0.f);
    float v1 = fmaxf(v[1] + p0[1] + p1[1], 0.f);
    size_t fo = ((size_t)b * NVRT + row) * 128 + c0;
    *(f32x2*)(outf + fo) = (f32x2){v0, v1};
    float p[3];
#pragma unroll
    for (int j = 0; j < 3; j++){
      p[j] = v0 * wl1[c0*3 + j] + v1 * wl1[c0*3 + 3 + j];
#pragma unroll
      for (int off = 1; off < 64; off <<= 1)
        p[j] += __shfl_xor(p[j], off);
    }
    if (lane == 0){
      size_t po_ = ((size_t)b * NVRT + row) * 3;
#pragma unroll
      for (int j = 0; j < 3; j++)
        opos[po_ + j] = pos[po_ + j] + tanhf(p[j] + bl1[j]);
    }
  }
}

// ================================================================ host
extern "C" void kernel_launch(void* const* d_in, const int* in_sizes, int n_in,
                              void* d_out, int out_size, void* d_ws, size_t ws_size,
                              hipStream_t stream)
{
  const float* conv[4] = {(const float*)d_in[0], (const float*)d_in[1],
                          (const float*)d_in[2], (const float*)d_in[3]};
  const float* adj   = (const float*)d_in[4];
  const float* pos   = (const float*)d_in[5];
  const float* vfeat = (const float*)d_in[6];
  const float* wlin0 = (const float*)d_in[7];
  const float* blin0 = (const float*)d_in[8];
  const float* gw[6] = {(const float*)d_in[9],  (const float*)d_in[10],
                        (const float*)d_in[11], (const float*)d_in[12],
                        (const float*)d_in[13], (const float*)d_in[14]};
  const float* wlin1 = (const float*)d_in[15];
  const float* blin1 = (const float*)d_in[16];

  char* ws = (char*)d_ws;
  size_t off = 0;
  auto take = [&](size_t bytes)->char* {
    char* p = ws + off;
    off += (bytes + 255) & ~(size_t)255;
    return p;
  };
  unsigned short* ftT  = (unsigned short*)take(FT_TOT * 2);
  float*          meta = (float*)take((size_t)NB*NVRT*32*4);
  unsigned short* adjP = (unsigned short*)take((size_t)NB*NRB2*NKT*4096);
  unsigned short* wl0p = (unsigned short*)take((size_t)3840*128*2);
  unsigned short* w0p0 = (unsigned short*)take((size_t)288*128*2);
  unsigned short* w1p0 = (unsigned short*)take((size_t)288*128*2);
  unsigned short* w0p1 = (unsigned short*)take((size_t)160*128*2);
  unsigned short* w1p1 = (unsigned short*)take((size_t)160*128*2);
  unsigned short* w0p2 = (unsigned short*)take((size_t)160*128*2);
  unsigned short* w1p2 = (unsigned short*)take((size_t)160*128*2);
  unsigned short* vf   = (unsigned short*)take((size_t)NB*MP*288*2);
  unsigned short* x1   = (unsigned short*)take((size_t)NB*MP*160*2);
  unsigned short* x2   = (unsigned short*)take((size_t)NB*MP*160*2);
  float*          y0   = (float*)take((size_t)NB*MP*128*4);
  unsigned short* y1p  = (unsigned short*)take((size_t)NB*MP*128*2);
  float*          pl0  = (float*)take((size_t)4*NB*MP*128*4);
  float*          pa   = (float*)take((size_t)2*NB*MP*128*4);

  float* out_pos  = (float*)d_out;
  float* out_feat = out_pos + (size_t)NB*NVRT*3;

  // 1. transposes (all 4 maps, one dispatch)
  k_transpose_all<<<dim3(1536, NB), dim3(32, 8), 0, stream>>>(conv[0], conv[1], conv[2], conv[3], ftT);
  // 2. weight packing (one dispatch)
  PWArgs pw;
  pw.src[0]=wlin0; pw.dst[0]=wl0p; pw.ksrc[0]=3840; pw.nsrc[0]=128;
  pw.src[1]=gw[0]; pw.dst[1]=w0p0; pw.ksrc[1]=259;  pw.nsrc[1]=131;
  pw.src[2]=gw[1]; pw.dst[2]=w1p0; pw.ksrc[2]=259;  pw.nsrc[2]=131;
  pw.src[3]=gw[2]; pw.dst[3]=w0p1; pw.ksrc[3]=131;  pw.nsrc[3]=128;
  pw.src[4]=gw[3]; pw.dst[4]=w1p1; pw.ksrc[4]=131;  pw.nsrc[4]=128;
  pw.src[5]=gw[4]; pw.dst[5]=w0p2; pw.ksrc[5]=131;  pw.nsrc[5]=128;
  pw.src[6]=gw[5]; pw.dst[6]=w1p2; pw.ksrc[6]=131;  pw.nsrc[6]=128;
  k_packw_all<<<2528, 256, 0, stream>>>(pw);
  // 3. meta + vf base + pads (one dispatch)
  k_prep<<<dim3(MP, NB), 64, 0, stream>>>(vfeat, pos, meta, vf, x1, x2);
  // 4. fused vert_align + lin0 (split-K) + epilogue
  k_lin0s<<<dim3(NRB2, 4, NB), 256, 0, stream>>>(ftT, meta, wl0p, pl0);
  k_lin0e<<<(NB*NVRT*32 + 255)/256, 256, 0, stream>>>(pl0, blin0, vf);
  // 5. pack adjacency to bf16 swizzled tiles
  k_adjpack<<<dim3(NKT, NRB2, NB), 256, 0, stream>>>(adj, adjP);
  // 6-8. three graph convs (split-K adj + epilogue)
  k_xw2<288><<<dim3(NRB2, NB), 256, 0, stream>>>(vf, w0p0, w1p0, y0, y1p);
  k_adjs<<<dim3(NRB2, 2, NB), 256, 0, stream>>>(adjP, y1p, pa);
  k_adje<0><<<(NB*NVRT*32 + 255)/256, 256, 0, stream>>>(y0, pa, x1, nullptr, nullptr, nullptr, nullptr, nullptr);
  k_xw2<160><<<dim3(NRB2, NB), 256, 0, stream>>>(x1, w0p1, w1p1, y0, y1p);
  k_adjs<<<dim3(NRB2, 2, NB), 256, 0, stream>>>(adjP, y1p, pa);
  k_adje<0><<<(NB*NVRT*32 + 255)/256, 256, 0, stream>>>(y0, pa, x2, nullptr, nullptr, nullptr, nullptr, nullptr);
  k_xw2<160><<<dim3(NRB2, NB), 256, 0, stream>>>(x2, w0p2, w1p2, y0, y1p);
  k_adjs<<<dim3(NRB2, 2, NB), 256, 0, stream>>>(adjP, y1p, pa);
  // 9. final epilogue: out_feat + fused position head
  k_adje<1><<<NB*NVRT/4, 256, 0, stream>>>(y0, pa, nullptr, out_feat, pos, wlin1, blin1, out_pos);
  (void)in_sizes; (void)n_in; (void)out_size; (void)ws_size;
}